// Round 20
// baseline (34.851 us; speedup 1.0000x reference)
//
#include <hip/hip_runtime.h>

#define BB 64
#define KK 4096
#define DD 512
#define HH 512

typedef __attribute__((ext_vector_type(8))) short bf16x8;
typedef __attribute__((ext_vector_type(4))) float f32x4;
typedef __attribute__((ext_vector_type(2))) float f32x2;

// float -> bf16 bits, round-to-nearest-even
__device__ __forceinline__ unsigned short f2b(float f) {
  unsigned u = __float_as_uint(f);
  unsigned r = u + 0x7fffu + ((u >> 16) & 1u);
  return (unsigned short)(r >> 16);
}

// packed 2xf32 helpers — elementwise, same rounding as scalar fmaf/fmaxf
__device__ __forceinline__ f32x2 pk_max0(f32x2 a) {
#if __has_builtin(__builtin_elementwise_max)
  f32x2 z = {0.f, 0.f};
  return __builtin_elementwise_max(a, z);
#else
  f32x2 r; r.x = fmaxf(a.x, 0.f); r.y = fmaxf(a.y, 0.f); return r;
#endif
}
__device__ __forceinline__ f32x2 pk_fma(f32x2 a, f32x2 b, f32x2 c) {
#if __has_builtin(__builtin_elementwise_fma)
  return __builtin_elementwise_fma(a, b, c);
#else
  f32x2 r; r.x = fmaf(a.x, b.x, c.x); r.y = fmaf(a.y, b.y, c.y); return r;
#endif
}

// Fragment chunk = 512 shorts = [64 lanes][8 bf16] = 1KB, coalesced per wave.
//  qp [c = bt*16+dt]:  lane l: q[bt*16+(l&15)][dt*32+(l>>4)*8+j]   (bt<4, dt<16)
//  W1p[c = ht*32+dtg]: lane l: W1[dtg*32+(l>>4)*8+j][ht*16+(l&15)] (ht<32, dtg<32)
//  kp [c = kt*16+dt]:  lane l: kemb[kt*16+(l&15)][dt*32+(l>>4)*8+j] (kt<256, dt<16)
// mfma(A=W1p-frag, B=data-frag): D row(M)=h=lg*4+r, col(N)=lm.
// SESSION RULES: single-GEMM-phase fused2 + staging waves is the ONLY fused
// shape that passes (R7/R8/R14/R19 all fail); no per-block device fences
// (R11); no serial fp32 tails (R12); qh kernel not removable (R14/R15/R16).

// ---------------- K1: prep (pack everything) — R13 verbatim -----------------
__global__ __launch_bounds__(256) void prep_kernel(
    const int* __restrict__ xq, const float* __restrict__ qemb,
    const float* __restrict__ W1, const float* __restrict__ kemb,
    unsigned short* __restrict__ qp, unsigned short* __restrict__ W1p,
    unsigned short* __restrict__ kp) {
  const int bid = blockIdx.x, t = threadIdx.x;
  if (bid < 16) {
    const int w = t >> 6, l = t & 63;
    const int chunk = bid * 4 + w;           // 0..63
    const int bt = chunk >> 4, dt = chunk & 15;
    const int brow = bt * 16 + (l & 15);
    const int row = xq[brow];
    const int d = dt * 32 + (l >> 4) * 8;
    const float4 f0 = *(const float4*)(qemb + (long)row * DD + d);
    const float4 f1 = *(const float4*)(qemb + (long)row * DD + d + 4);
    bf16x8 o;
    o[0] = (short)f2b(f0.x); o[1] = (short)f2b(f0.y);
    o[2] = (short)f2b(f0.z); o[3] = (short)f2b(f0.w);
    o[4] = (short)f2b(f1.x); o[5] = (short)f2b(f1.y);
    o[6] = (short)f2b(f1.z); o[7] = (short)f2b(f1.w);
    *(bf16x8*)(qp + chunk * 512 + l * 8) = o;
  } else if (bid < 528) {
    __shared__ float tile[32][33];           // [d_local][h_local]
    const int tb = bid - 16;                 // 0..511
    const int d0 = (tb & 31) * 32;           // 0..1023 (full W1)
    const int h0 = (tb >> 5) * 32;           // 0..511
    for (int i = t; i < 1024; i += 256) {
      int r = i >> 5, c = i & 31;
      tile[r][c] = W1[(long)(d0 + r) * HH + h0 + c];   // coalesced over h
    }
    __syncthreads();
    const int i = t * 4;
    const int ci = i >> 9, li = i & 511;
    const int l = li >> 3, j0 = li & 7;      // j0 in {0,4}
    ushort4 o;
    o.x = f2b(tile[(l >> 4) * 8 + j0 + 0][ci * 16 + (l & 15)]);
    o.y = f2b(tile[(l >> 4) * 8 + j0 + 1][ci * 16 + (l & 15)]);
    o.z = f2b(tile[(l >> 4) * 8 + j0 + 2][ci * 16 + (l & 15)]);
    o.w = f2b(tile[(l >> 4) * 8 + j0 + 3][ci * 16 + (l & 15)]);
    const int cglob = ((tb >> 5) * 2 + ci) * 32 + (tb & 31);
    *(ushort4*)(W1p + cglob * 512 + li) = o;
  } else {
    #pragma unroll
    for (int rep = 0; rep < 2; ++rep) {
      const int tt = (bid - 528) * 512 + t * 2 + rep;
      const int chunk = tt >> 6, l = tt & 63;
      const int kt = chunk >> 4, dt = chunk & 15;
      const int k = kt * 16 + (l & 15);
      const int d = dt * 32 + (l >> 4) * 8;
      const float4 f0 = *(const float4*)(kemb + (long)k * DD + d);
      const float4 f1 = *(const float4*)(kemb + (long)k * DD + d + 4);
      bf16x8 o;
      o[0] = (short)f2b(f0.x); o[1] = (short)f2b(f0.y);
      o[2] = (short)f2b(f0.z); o[3] = (short)f2b(f0.w);
      o[4] = (short)f2b(f1.x); o[5] = (short)f2b(f1.y);
      o[6] = (short)f2b(f1.z); o[7] = (short)f2b(f1.w);
      *(bf16x8*)(kp + (long)chunk * 512 + l * 8) = o;
    }
  }
}

// ---------------- K2: qhT[h][b] = b1[h] + (q @ W1a)^T via MFMA — R13 verbatim
__global__ __launch_bounds__(256) void qh_mfma_kernel(
    const unsigned short* __restrict__ qp,
    const unsigned short* __restrict__ W1p,
    const float* __restrict__ b1, float* __restrict__ qhT) {
  const int t = threadIdx.x;
  const int w = t >> 6, l = t & 63;
  const int ht = blockIdx.x;
  const unsigned short* ap = W1p + (ht * 32) * 512 + l * 8;   // dtg 0..15
  const unsigned short* bp = qp + (w * 16) * 512 + l * 8;
  f32x4 acc = {};
  #pragma unroll
  for (int dt = 0; dt < 16; ++dt) {
    bf16x8 a = *(const bf16x8*)(ap + dt * 512);
    bf16x8 b = *(const bf16x8*)(bp + dt * 512);
    acc = __builtin_amdgcn_mfma_f32_16x16x32_bf16(a, b, acc, 0, 0, 0);
  }
  const int lm = l & 15, lg = l >> 4;
  const float4 bv = *(const float4*)(b1 + ht * 16 + lg * 4);
  const float bb[4] = {bv.x, bv.y, bv.z, bv.w};
  #pragma unroll
  for (int r = 0; r < 4; ++r)
    qhT[(ht * 16 + lg * 4 + r) * BB + w * 16 + lm] = acc[r] + bb[r];
}

// ---------------- K3: fused kh-GEMM + relu-dot (R18 body, unroll-8) ---------
// grid (64 kt, 8 hg) x 512 thr. Waves 0-3: khT_mfma body (unroll 8: more
// loads in flight to cover L2 latency) -> LDS kh. Waves 4-7: stage qs + w2s.
// One barrier; packed f32x2 consume; pstage alias (stride 17).
__global__ __launch_bounds__(512) void fused2_kernel(
    const unsigned short* __restrict__ kp,
    const unsigned short* __restrict__ W1p,
    const float* __restrict__ qhT, const float* __restrict__ w2,
    float* __restrict__ part) {
  __shared__ float kh[64][68];
  __shared__ float qs[64][68];
  __shared__ float w2s[64];
  const int t = threadIdx.x;
  const int w = t >> 6, l = t & 63;
  const int hbase = blockIdx.y * 64;
  if (w < 4) {
    // === khT_mfma body (R6/R9/R10-proven), w in 0..3; unroll 4 -> 8 ===
    const int kt0 = blockIdx.x * 4 + (w & 1) * 2;   // chunk units (16 k)
    const int ht0 = blockIdx.y * 4 + (w >> 1) * 2;  // chunk units (16 h)
    const unsigned short* ap = W1p + (long)(ht0 * 32 + 16) * 512 + l * 8; // dtg 16..31
    const unsigned short* bp = kp + (long)(kt0 * 16) * 512 + l * 8;
    f32x4 acc[2][2] = {};
    #pragma unroll 8
    for (int dt = 0; dt < 16; ++dt) {
      bf16x8 a0 = *(const bf16x8*)(ap + dt * 512);
      bf16x8 a1 = *(const bf16x8*)(ap + 32 * 512 + dt * 512);
      bf16x8 b0 = *(const bf16x8*)(bp + dt * 512);
      bf16x8 b1 = *(const bf16x8*)(bp + 16 * 512 + dt * 512);
      acc[0][0] = __builtin_amdgcn_mfma_f32_16x16x32_bf16(a0, b0, acc[0][0], 0, 0, 0);
      acc[0][1] = __builtin_amdgcn_mfma_f32_16x16x32_bf16(a0, b1, acc[0][1], 0, 0, 0);
      acc[1][0] = __builtin_amdgcn_mfma_f32_16x16x32_bf16(a1, b0, acc[1][0], 0, 0, 0);
      acc[1][1] = __builtin_amdgcn_mfma_f32_16x16x32_bf16(a1, b1, acc[1][1], 0, 0, 0);
    }
    const int lm = l & 15, lg = l >> 4;
    #pragma unroll
    for (int mt = 0; mt < 2; ++mt)
      #pragma unroll
      for (int nt = 0; nt < 2; ++nt)
        #pragma unroll
        for (int r = 0; r < 4; ++r)
          kh[((w >> 1) * 2 + mt) * 16 + lg * 4 + r][((w & 1) * 2 + nt) * 16 + lm] =
              acc[mt][nt][r];
  } else {
    // === waves 4-7: stage qs (h-major) and w2s ===
    const int tt = t - 256;
    for (int i = tt; i < 1024; i += 256) {
      const int h = i >> 4, b4 = (i & 15) * 4;
      *(float4*)&qs[h][b4] = *(const float4*)(qhT + (hbase + h) * BB + b4);
    }
    if (tt < 64) w2s[tt] = w2[hbase + tt];
  }
  __syncthreads();
  // === consume: packed f32x2 (R18-proven), unroll 8 ===
  const int kq = t & 15, bq = (t >> 4) & 15, hh = t >> 8;
  const int h0 = hh * 32;
  f32x2 acc2[4][2] = {};                 // [jb][jk-pair]
  #pragma unroll 8
  for (int i = 0; i < 32; ++i) {
    const float4 kv = *(const float4*)&kh[h0 + i][kq * 4];
    const float4 q4 = *(const float4*)&qs[h0 + i][bq * 4];
    const float wv = w2s[h0 + i];
    const f32x2 wv2 = {wv, wv};
    const f32x2 k01 = {kv.x, kv.y};
    const f32x2 k23 = {kv.z, kv.w};
    const float qq[4] = {q4.x, q4.y, q4.z, q4.w};
    #pragma unroll
    for (int jb = 0; jb < 4; ++jb) {
      const f32x2 q2 = {qq[jb], qq[jb]};
      acc2[jb][0] = pk_fma(pk_max0(q2 + k01), wv2, acc2[jb][0]);
      acc2[jb][1] = pk_fma(pk_max0(q2 + k23), wv2, acc2[jb][1]);
    }
  }
  __syncthreads();                       // consume reads of kh done (alias next)
  float* pstage = &kh[0][0];             // alias onto dead kh; stride 17 words
  if (hh == 1) {
    #pragma unroll
    for (int jb = 0; jb < 4; ++jb) {
      pstage[(bq * 16 + kq) * 17 + jb * 4 + 0] = acc2[jb][0].x;
      pstage[(bq * 16 + kq) * 17 + jb * 4 + 1] = acc2[jb][0].y;
      pstage[(bq * 16 + kq) * 17 + jb * 4 + 2] = acc2[jb][1].x;
      pstage[(bq * 16 + kq) * 17 + jb * 4 + 3] = acc2[jb][1].y;
    }
  }
  __syncthreads();
  if (hh == 0) {
    #pragma unroll
    for (int jb = 0; jb < 4; ++jb) {
      float4 cv;
      cv.x = acc2[jb][0].x + pstage[(bq * 16 + kq) * 17 + jb * 4 + 0];
      cv.y = acc2[jb][0].y + pstage[(bq * 16 + kq) * 17 + jb * 4 + 1];
      cv.z = acc2[jb][1].x + pstage[(bq * 16 + kq) * 17 + jb * 4 + 2];
      cv.w = acc2[jb][1].y + pstage[(bq * 16 + kq) * 17 + jb * 4 + 3];
      *(float4*)(part + (long)(blockIdx.y * BB + bq * 4 + jb) * KK +
                 blockIdx.x * 64 + kq * 4) = cv;
    }
  }
}

// ---------------- K4: out[b][k] = b2 + sum_hs part[hs][b][k] — R6 verbatim --
__global__ __launch_bounds__(256) void reduce_kernel(
    const float* __restrict__ part, const float* __restrict__ b2,
    float* __restrict__ out) {
  const int tid = blockIdx.x * 256 + threadIdx.x;   // 65536 float4 tasks
  const int b = tid >> 10, kq = tid & 1023;
  const float bias = b2[0];
  float4 s = make_float4(bias, bias, bias, bias);
  #pragma unroll
  for (int hs = 0; hs < 8; ++hs) {
    const float4 p = *(const float4*)(part + (long)(hs * BB + b) * KK + kq * 4);
    s.x += p.x; s.y += p.y; s.z += p.z; s.w += p.w;
  }
  *(float4*)(out + (long)b * KK + kq * 4) = s;
}

extern "C" void kernel_launch(void* const* d_in, const int* in_sizes, int n_in,
                              void* d_out, int out_size, void* d_ws, size_t ws_size,
                              hipStream_t stream) {
  const int*   xq   = (const int*)d_in[0];
  const float* qemb = (const float*)d_in[1];
  const float* kemb = (const float*)d_in[2];
  const float* W1   = (const float*)d_in[3];
  const float* b1   = (const float*)d_in[4];
  const float* W2   = (const float*)d_in[5];
  const float* b2   = (const float*)d_in[6];
  float* out = (float*)d_out;

  float* qhT  = (float*)d_ws;                         // 128 KB
  float* part = qhT + HH * BB;                        // 8 MB (8 slices)
  unsigned short* qp  = (unsigned short*)(part + (long)8 * BB * KK); // 64 KB
  unsigned short* W1p = qp + BB * DD;                 // 1 MB (full W1)
  unsigned short* kp  = W1p + 32 * 32 * 512;          // 4 MB

  hipLaunchKernelGGL(prep_kernel, dim3(1040), dim3(256), 0, stream,
                     xq, qemb, W1, kemb, qp, W1p, kp);
  hipLaunchKernelGGL(qh_mfma_kernel, dim3(32), dim3(256), 0, stream,
                     qp, W1p, b1, qhT);
  hipLaunchKernelGGL(fused2_kernel, dim3(KK / 64, 8), dim3(512), 0, stream,
                     kp, W1p, qhT, W2, part);
  hipLaunchKernelGGL(reduce_kernel, dim3(256), dim3(256), 0, stream,
                     part, b2, out);
}

// Round 21
// 33.355 us; speedup vs baseline: 1.0448x; 1.0448x over previous
//
#include <hip/hip_runtime.h>

#define BB 64
#define KK 4096
#define DD 512
#define HH 512

typedef __attribute__((ext_vector_type(8))) short bf16x8;
typedef __attribute__((ext_vector_type(4))) float f32x4;
typedef __attribute__((ext_vector_type(2))) float f32x2;

// float -> bf16 bits, round-to-nearest-even
__device__ __forceinline__ unsigned short f2b(float f) {
  unsigned u = __float_as_uint(f);
  unsigned r = u + 0x7fffu + ((u >> 16) & 1u);
  return (unsigned short)(r >> 16);
}

// packed 2xf32 helpers — elementwise, same rounding as scalar fmaf/fmaxf
__device__ __forceinline__ f32x2 pk_max0(f32x2 a) {
#if __has_builtin(__builtin_elementwise_max)
  f32x2 z = {0.f, 0.f};
  return __builtin_elementwise_max(a, z);
#else
  f32x2 r; r.x = fmaxf(a.x, 0.f); r.y = fmaxf(a.y, 0.f); return r;
#endif
}
__device__ __forceinline__ f32x2 pk_fma(f32x2 a, f32x2 b, f32x2 c) {
#if __has_builtin(__builtin_elementwise_fma)
  return __builtin_elementwise_fma(a, b, c);
#else
  f32x2 r; r.x = fmaf(a.x, b.x, c.x); r.y = fmaf(a.y, b.y, c.y); return r;
#endif
}

// Fragment chunk = 512 shorts = [64 lanes][8 bf16] = 1KB, coalesced per wave.
//  qp [c = bt*16+dt]:  lane l: q[bt*16+(l&15)][dt*32+(l>>4)*8+j]   (bt<4, dt<16)
//  W1p[c = ht*32+dtg]: lane l: W1[dtg*32+(l>>4)*8+j][ht*16+(l&15)] (ht<32, dtg<32)
//  kp [c = kt*16+dt]:  lane l: kemb[kt*16+(l&15)][dt*32+(l>>4)*8+j] (kt<256, dt<16)
// mfma(A=W1p-frag, B=data-frag): D row(M)=h=lg*4+r, col(N)=lm.
// SESSION RULES: single-GEMM-phase fused2 + staging waves is the ONLY fused
// shape that passes (R7/R8/R14/R19 all fail); no per-block device fences
// (R11); no serial fp32 tails (R12); qh kernel not removable (R14/R15/R16);
// GEMM unroll 4 optimal (R20: unroll 8 regressed).

// ---------------- K1: prep (pack everything) — R13 verbatim -----------------
__global__ __launch_bounds__(256) void prep_kernel(
    const int* __restrict__ xq, const float* __restrict__ qemb,
    const float* __restrict__ W1, const float* __restrict__ kemb,
    unsigned short* __restrict__ qp, unsigned short* __restrict__ W1p,
    unsigned short* __restrict__ kp) {
  const int bid = blockIdx.x, t = threadIdx.x;
  if (bid < 16) {
    const int w = t >> 6, l = t & 63;
    const int chunk = bid * 4 + w;           // 0..63
    const int bt = chunk >> 4, dt = chunk & 15;
    const int brow = bt * 16 + (l & 15);
    const int row = xq[brow];
    const int d = dt * 32 + (l >> 4) * 8;
    const float4 f0 = *(const float4*)(qemb + (long)row * DD + d);
    const float4 f1 = *(const float4*)(qemb + (long)row * DD + d + 4);
    bf16x8 o;
    o[0] = (short)f2b(f0.x); o[1] = (short)f2b(f0.y);
    o[2] = (short)f2b(f0.z); o[3] = (short)f2b(f0.w);
    o[4] = (short)f2b(f1.x); o[5] = (short)f2b(f1.y);
    o[6] = (short)f2b(f1.z); o[7] = (short)f2b(f1.w);
    *(bf16x8*)(qp + chunk * 512 + l * 8) = o;
  } else if (bid < 528) {
    __shared__ float tile[32][33];           // [d_local][h_local]
    const int tb = bid - 16;                 // 0..511
    const int d0 = (tb & 31) * 32;           // 0..1023 (full W1)
    const int h0 = (tb >> 5) * 32;           // 0..511
    for (int i = t; i < 1024; i += 256) {
      int r = i >> 5, c = i & 31;
      tile[r][c] = W1[(long)(d0 + r) * HH + h0 + c];   // coalesced over h
    }
    __syncthreads();
    const int i = t * 4;
    const int ci = i >> 9, li = i & 511;
    const int l = li >> 3, j0 = li & 7;      // j0 in {0,4}
    ushort4 o;
    o.x = f2b(tile[(l >> 4) * 8 + j0 + 0][ci * 16 + (l & 15)]);
    o.y = f2b(tile[(l >> 4) * 8 + j0 + 1][ci * 16 + (l & 15)]);
    o.z = f2b(tile[(l >> 4) * 8 + j0 + 2][ci * 16 + (l & 15)]);
    o.w = f2b(tile[(l >> 4) * 8 + j0 + 3][ci * 16 + (l & 15)]);
    const int cglob = ((tb >> 5) * 2 + ci) * 32 + (tb & 31);
    *(ushort4*)(W1p + cglob * 512 + li) = o;
  } else {
    #pragma unroll
    for (int rep = 0; rep < 2; ++rep) {
      const int tt = (bid - 528) * 512 + t * 2 + rep;
      const int chunk = tt >> 6, l = tt & 63;
      const int kt = chunk >> 4, dt = chunk & 15;
      const int k = kt * 16 + (l & 15);
      const int d = dt * 32 + (l >> 4) * 8;
      const float4 f0 = *(const float4*)(kemb + (long)k * DD + d);
      const float4 f1 = *(const float4*)(kemb + (long)k * DD + d + 4);
      bf16x8 o;
      o[0] = (short)f2b(f0.x); o[1] = (short)f2b(f0.y);
      o[2] = (short)f2b(f0.z); o[3] = (short)f2b(f0.w);
      o[4] = (short)f2b(f1.x); o[5] = (short)f2b(f1.y);
      o[6] = (short)f2b(f1.z); o[7] = (short)f2b(f1.w);
      *(bf16x8*)(kp + (long)chunk * 512 + l * 8) = o;
    }
  }
}

// ---------------- K2: qhT[h][b] = b1[h] + (q @ W1a)^T via MFMA — R13 verbatim
__global__ __launch_bounds__(256) void qh_mfma_kernel(
    const unsigned short* __restrict__ qp,
    const unsigned short* __restrict__ W1p,
    const float* __restrict__ b1, float* __restrict__ qhT) {
  const int t = threadIdx.x;
  const int w = t >> 6, l = t & 63;
  const int ht = blockIdx.x;
  const unsigned short* ap = W1p + (ht * 32) * 512 + l * 8;   // dtg 0..15
  const unsigned short* bp = qp + (w * 16) * 512 + l * 8;
  f32x4 acc = {};
  #pragma unroll
  for (int dt = 0; dt < 16; ++dt) {
    bf16x8 a = *(const bf16x8*)(ap + dt * 512);
    bf16x8 b = *(const bf16x8*)(bp + dt * 512);
    acc = __builtin_amdgcn_mfma_f32_16x16x32_bf16(a, b, acc, 0, 0, 0);
  }
  const int lm = l & 15, lg = l >> 4;
  const float4 bv = *(const float4*)(b1 + ht * 16 + lg * 4);
  const float bb[4] = {bv.x, bv.y, bv.z, bv.w};
  #pragma unroll
  for (int r = 0; r < 4; ++r)
    qhT[(ht * 16 + lg * 4 + r) * BB + w * 16 + lm] = acc[r] + bb[r];
}

// ---------------- K3: fused kh-GEMM + relu-dot (R13 body, packed consume) ---
// grid (64 kt, 8 hg) x 512 thr. Waves 0-3: khT_mfma body -> LDS kh.
// Waves 4-7: stage qs + w2s. One barrier; consume uses f32x2 packed
// add/max/fma (element-order & rounding identical to scalar). pstage alias.
__global__ __launch_bounds__(512) void fused2_kernel(
    const unsigned short* __restrict__ kp,
    const unsigned short* __restrict__ W1p,
    const float* __restrict__ qhT, const float* __restrict__ w2,
    float* __restrict__ part) {
  __shared__ float kh[64][68];
  __shared__ float qs[64][68];
  __shared__ float w2s[64];
  const int t = threadIdx.x;
  const int w = t >> 6, l = t & 63;
  const int hbase = blockIdx.y * 64;
  if (w < 4) {
    // === khT_mfma body (R6/R9/R10-proven), w in 0..3 ===
    const int kt0 = blockIdx.x * 4 + (w & 1) * 2;   // chunk units (16 k)
    const int ht0 = blockIdx.y * 4 + (w >> 1) * 2;  // chunk units (16 h)
    const unsigned short* ap = W1p + (long)(ht0 * 32 + 16) * 512 + l * 8; // dtg 16..31
    const unsigned short* bp = kp + (long)(kt0 * 16) * 512 + l * 8;
    f32x4 acc[2][2] = {};
    #pragma unroll 4
    for (int dt = 0; dt < 16; ++dt) {
      bf16x8 a0 = *(const bf16x8*)(ap + dt * 512);
      bf16x8 a1 = *(const bf16x8*)(ap + 32 * 512 + dt * 512);
      bf16x8 b0 = *(const bf16x8*)(bp + dt * 512);
      bf16x8 b1 = *(const bf16x8*)(bp + 16 * 512 + dt * 512);
      acc[0][0] = __builtin_amdgcn_mfma_f32_16x16x32_bf16(a0, b0, acc[0][0], 0, 0, 0);
      acc[0][1] = __builtin_amdgcn_mfma_f32_16x16x32_bf16(a0, b1, acc[0][1], 0, 0, 0);
      acc[1][0] = __builtin_amdgcn_mfma_f32_16x16x32_bf16(a1, b0, acc[1][0], 0, 0, 0);
      acc[1][1] = __builtin_amdgcn_mfma_f32_16x16x32_bf16(a1, b1, acc[1][1], 0, 0, 0);
    }
    const int lm = l & 15, lg = l >> 4;
    #pragma unroll
    for (int mt = 0; mt < 2; ++mt)
      #pragma unroll
      for (int nt = 0; nt < 2; ++nt)
        #pragma unroll
        for (int r = 0; r < 4; ++r)
          kh[((w >> 1) * 2 + mt) * 16 + lg * 4 + r][((w & 1) * 2 + nt) * 16 + lm] =
              acc[mt][nt][r];
  } else {
    // === waves 4-7: stage qs (h-major) and w2s ===
    const int tt = t - 256;
    for (int i = tt; i < 1024; i += 256) {
      const int h = i >> 4, b4 = (i & 15) * 4;
      *(float4*)&qs[h][b4] = *(const float4*)(qhT + (hbase + h) * BB + b4);
    }
    if (tt < 64) w2s[tt] = w2[hbase + tt];
  }
  __syncthreads();
  // === consume: packed f32x2 (element-identical to R13 scalar loop) ===
  const int kq = t & 15, bq = (t >> 4) & 15, hh = t >> 8;
  const int h0 = hh * 32;
  f32x2 acc2[4][2] = {};                 // [jb][jk-pair]
  #pragma unroll 4
  for (int i = 0; i < 32; ++i) {
    const float4 kv = *(const float4*)&kh[h0 + i][kq * 4];
    const float4 q4 = *(const float4*)&qs[h0 + i][bq * 4];
    const float wv = w2s[h0 + i];
    const f32x2 wv2 = {wv, wv};
    const f32x2 k01 = {kv.x, kv.y};
    const f32x2 k23 = {kv.z, kv.w};
    const float qq[4] = {q4.x, q4.y, q4.z, q4.w};
    #pragma unroll
    for (int jb = 0; jb < 4; ++jb) {
      const f32x2 q2 = {qq[jb], qq[jb]};
      acc2[jb][0] = pk_fma(pk_max0(q2 + k01), wv2, acc2[jb][0]);
      acc2[jb][1] = pk_fma(pk_max0(q2 + k23), wv2, acc2[jb][1]);
    }
  }
  __syncthreads();                       // consume reads of kh done (alias next)
  float* pstage = &kh[0][0];             // alias onto dead kh; stride 17 words
  if (hh == 1) {
    #pragma unroll
    for (int jb = 0; jb < 4; ++jb) {
      pstage[(bq * 16 + kq) * 17 + jb * 4 + 0] = acc2[jb][0].x;
      pstage[(bq * 16 + kq) * 17 + jb * 4 + 1] = acc2[jb][0].y;
      pstage[(bq * 16 + kq) * 17 + jb * 4 + 2] = acc2[jb][1].x;
      pstage[(bq * 16 + kq) * 17 + jb * 4 + 3] = acc2[jb][1].y;
    }
  }
  __syncthreads();
  if (hh == 0) {
    #pragma unroll
    for (int jb = 0; jb < 4; ++jb) {
      float4 cv;
      cv.x = acc2[jb][0].x + pstage[(bq * 16 + kq) * 17 + jb * 4 + 0];
      cv.y = acc2[jb][0].y + pstage[(bq * 16 + kq) * 17 + jb * 4 + 1];
      cv.z = acc2[jb][1].x + pstage[(bq * 16 + kq) * 17 + jb * 4 + 2];
      cv.w = acc2[jb][1].y + pstage[(bq * 16 + kq) * 17 + jb * 4 + 3];
      *(float4*)(part + (long)(blockIdx.y * BB + bq * 4 + jb) * KK +
                 blockIdx.x * 64 + kq * 4) = cv;
    }
  }
}

// ---------------- K4: out[b][k] = b2 + sum_hs part[hs][b][k] — R6 verbatim --
__global__ __launch_bounds__(256) void reduce_kernel(
    const float* __restrict__ part, const float* __restrict__ b2,
    float* __restrict__ out) {
  const int tid = blockIdx.x * 256 + threadIdx.x;   // 65536 float4 tasks
  const int b = tid >> 10, kq = tid & 1023;
  const float bias = b2[0];
  float4 s = make_float4(bias, bias, bias, bias);
  #pragma unroll
  for (int hs = 0; hs < 8; ++hs) {
    const float4 p = *(const float4*)(part + (long)(hs * BB + b) * KK + kq * 4);
    s.x += p.x; s.y += p.y; s.z += p.z; s.w += p.w;
  }
  *(float4*)(out + (long)b * KK + kq * 4) = s;
}

extern "C" void kernel_launch(void* const* d_in, const int* in_sizes, int n_in,
                              void* d_out, int out_size, void* d_ws, size_t ws_size,
                              hipStream_t stream) {
  const int*   xq   = (const int*)d_in[0];
  const float* qemb = (const float*)d_in[1];
  const float* kemb = (const float*)d_in[2];
  const float* W1   = (const float*)d_in[3];
  const float* b1   = (const float*)d_in[4];
  const float* W2   = (const float*)d_in[5];
  const float* b2   = (const float*)d_in[6];
  float* out = (float*)d_out;

  float* qhT  = (float*)d_ws;                         // 128 KB
  float* part = qhT + HH * BB;                        // 8 MB (8 slices)
  unsigned short* qp  = (unsigned short*)(part + (long)8 * BB * KK); // 64 KB
  unsigned short* W1p = qp + BB * DD;                 // 1 MB (full W1)
  unsigned short* kp  = W1p + 32 * 32 * 512;          // 4 MB

  hipLaunchKernelGGL(prep_kernel, dim3(1040), dim3(256), 0, stream,
                     xq, qemb, W1, kemb, qp, W1p, kp);
  hipLaunchKernelGGL(qh_mfma_kernel, dim3(32), dim3(256), 0, stream,
                     qp, W1p, b1, qhT);
  hipLaunchKernelGGL(fused2_kernel, dim3(KK / 64, 8), dim3(512), 0, stream,
                     kp, W1p, qhT, W2, part);
  hipLaunchKernelGGL(reduce_kernel, dim3(256), dim3(256), 0, stream,
                     part, b2, out);
}